// Round 1
// baseline (1008.094 us; speedup 1.0000x reference)
//
#include <hip/hip_runtime.h>
#include <hip/hip_bf16.h>
#include <cstdint>
#include <cstddef>

typedef __bf16 bf16x8 __attribute__((ext_vector_type(8)));
typedef float f32x4 __attribute__((ext_vector_type(4)));
typedef unsigned short u16x4 __attribute__((ext_vector_type(4)));
typedef unsigned short u16x8 __attribute__((ext_vector_type(8)));

namespace {
constexpr int kT = 8192;        // tokens
constexpr int kH = 1024;
constexpr int kE = 8;
constexpr int kI = 2752;
constexpr int kIP = 2816;       // I padded to 128 multiple... (22*128)
constexpr int kPairCap = 25728; // 201*128 >= 16384 + 8*127 (pad) + 8192 shared

constexpr size_t SZ_XB  = (size_t)kT * kH * 2;
constexpr size_t SZ_WB  = (size_t)kE * kIP * kH * 2;
constexpr size_t SZ_SB  = (size_t)kIP * kH * 2;
constexpr size_t SZ_HDN = (size_t)kPairCap * kIP * 2;

constexpr size_t OFF_XB  = 0;
constexpr size_t OFF_WGB = OFF_XB + SZ_XB;
constexpr size_t OFF_WUB = OFF_WGB + SZ_WB;
constexpr size_t OFF_WDB = OFF_WUB + SZ_WB;
constexpr size_t OFF_SGB = OFF_WDB + SZ_WB;
constexpr size_t OFF_SUB = OFF_SGB + SZ_SB;
constexpr size_t OFF_SDB = OFF_SUB + SZ_SB;
constexpr size_t OFF_HDN = OFF_SDB + SZ_SB;
constexpr size_t OFF_PT  = OFF_HDN + SZ_HDN;            // pair_token [kPairCap] int
constexpr size_t OFF_PW  = OFF_PT + (size_t)kPairCap*4; // pair_wt [kPairCap] f32
constexpr size_t OFF_CNT = OFF_PW + (size_t)kPairCap*4; // cnt[8]
constexpr size_t OFF_CUR = OFF_CNT + 256;               // cursor[8]
constexpr size_t OFF_SEG = OFF_CUR + 256;               // seg_off[10]
constexpr size_t OFF_TI  = OFF_SEG + 256;               // topk idx [kT*2]
constexpr size_t OFF_TW  = OFF_TI + (size_t)kT*2*4;     // topk wt  [kT*2]
constexpr size_t WS_NEED = OFF_TW + (size_t)kT*2*4;
}

__device__ __forceinline__ unsigned short f2bf(float f) {
  unsigned u = __builtin_bit_cast(unsigned, f);
  u += 0x7fffu + ((u >> 16) & 1u);
  return (unsigned short)(u >> 16);
}

// ---------- fp32 -> bf16 converts (with I-padding) ----------
__global__ __launch_bounds__(256) void k_conv_x(const float* __restrict__ src,
                                                unsigned short* __restrict__ dst) {
  int i = blockIdx.x * 256 + threadIdx.x;   // quad index, grid exact
  f32x4 v = reinterpret_cast<const f32x4*>(src)[i];
  u16x4 o;
  #pragma unroll
  for (int j = 0; j < 4; ++j) o[j] = f2bf(v[j]);
  reinterpret_cast<u16x4*>(dst)[i] = o;
}

// src [Eo, kI, kH] -> dst [Eo, kIP, kH], pad rows >= kI with zeros
__global__ __launch_bounds__(256) void k_conv_gateup(const float* __restrict__ src,
                                                     unsigned short* __restrict__ dst,
                                                     int Eo) {
  int i = blockIdx.x * 256 + threadIdx.x;   // quad index over Eo*kIP*256
  int c4 = i & 255;
  int r  = (i >> 8) % kIP;
  int e  = i / (256 * kIP);
  u16x4 o = (u16x4)0;
  if (r < kI) {
    f32x4 v = reinterpret_cast<const f32x4*>(src)[((size_t)e * kI + r) * 256 + c4];
    #pragma unroll
    for (int j = 0; j < 4; ++j) o[j] = f2bf(v[j]);
  }
  reinterpret_cast<u16x4*>(dst)[i] = o;
}

// src [Eo, kH, kI] -> dst [Eo, kH, kIP], pad cols >= kI with zeros
__global__ __launch_bounds__(256) void k_conv_down(const float* __restrict__ src,
                                                   unsigned short* __restrict__ dst,
                                                   int Eo) {
  int i = blockIdx.x * 256 + threadIdx.x;   // quad index over Eo*kH*704
  int c4 = i % 704;
  int rr = i / 704;
  int r  = rr % kH;
  int e  = rr / kH;
  u16x4 o = (u16x4)0;
  if (c4 < 688) {
    f32x4 v = reinterpret_cast<const f32x4*>(src)[((size_t)e * kH + r) * 688 + c4];
    #pragma unroll
    for (int j = 0; j < 4; ++j) o[j] = f2bf(v[j]);
  }
  reinterpret_cast<u16x4*>(dst)[i] = o;
}

// ---------- gate: softmax over 8 logits, top-2, renorm ----------
__global__ __launch_bounds__(256) void k_gate(const float* __restrict__ x,
                                              const float* __restrict__ gw,
                                              int* __restrict__ tki,
                                              float* __restrict__ tkw,
                                              int* __restrict__ cnt) {
  const int l = threadIdx.x & 63;
  const int t = blockIdx.x * 4 + (threadIdx.x >> 6);
  const float* xr = x + (size_t)t * kH + l * 16;
  float xv[16];
  #pragma unroll
  for (int j = 0; j < 16; j += 4) {
    f32x4 v = *reinterpret_cast<const f32x4*>(xr + j);
    xv[j] = v[0]; xv[j+1] = v[1]; xv[j+2] = v[2]; xv[j+3] = v[3];
  }
  float acc[kE];
  #pragma unroll
  for (int e = 0; e < kE; ++e) {
    const float* gr = gw + e * kH + l * 16;
    float s = 0.f;
    #pragma unroll
    for (int j = 0; j < 16; j += 4) {
      f32x4 g = *reinterpret_cast<const f32x4*>(gr + j);
      s += xv[j]*g[0] + xv[j+1]*g[1] + xv[j+2]*g[2] + xv[j+3]*g[3];
    }
    acc[e] = s;
  }
  #pragma unroll
  for (int e = 0; e < kE; ++e) {
    #pragma unroll
    for (int off = 32; off > 0; off >>= 1) acc[e] += __shfl_xor(acc[e], off, 64);
  }
  if (l == 0) {
    float m = acc[0];
    #pragma unroll
    for (int e = 1; e < kE; ++e) m = fmaxf(m, acc[e]);
    float p[kE]; float sum = 0.f;
    #pragma unroll
    for (int e = 0; e < kE; ++e) { p[e] = __expf(acc[e] - m); sum += p[e]; }
    float inv = 1.f / sum;
    int i1 = 0; float v1 = -1.f;
    #pragma unroll
    for (int e = 0; e < kE; ++e) { float s = p[e] * inv; if (s > v1) { v1 = s; i1 = e; } }
    int i2 = -1; float v2 = -1.f;
    #pragma unroll
    for (int e = 0; e < kE; ++e) {
      if (e == i1) continue;
      float s = p[e] * inv; if (s > v2) { v2 = s; i2 = e; }
    }
    float denom = v1 + v2 + 1e-20f;
    tki[t*2]   = i1; tki[t*2+1] = i2;
    tkw[t*2]   = v1 / denom; tkw[t*2+1] = v2 / denom;
    atomicAdd(&cnt[i1], 1); atomicAdd(&cnt[i2], 1);
  }
}

// ---------- segment offsets (padded to 128) ----------
__global__ void k_seg(const int* __restrict__ cnt, int* __restrict__ seg,
                      int* __restrict__ cur) {
  int off = 0;
  for (int e = 0; e < kE; ++e) {
    seg[e] = off; cur[e] = off;
    off += (cnt[e] + 127) & ~127;
  }
  seg[8] = off;
  seg[9] = off + kT;
}

// ---------- fill pair lists ----------
__global__ __launch_bounds__(256) void k_fill(const int* __restrict__ tki,
                                              const float* __restrict__ tkw,
                                              const int* __restrict__ seg,
                                              int* __restrict__ cur,
                                              int* __restrict__ pt,
                                              float* __restrict__ pw) {
  int i = blockIdx.x * 256 + threadIdx.x;
  if (i < kT * 2) {
    int e = tki[i];
    int pos = atomicAdd(&cur[e], 1);
    pt[pos] = i >> 1;
    pw[pos] = tkw[i];
  } else {
    int t = i - kT * 2;          // shared-expert segment, weight 1
    int pos = seg[8] + t;
    pt[pos] = t;
    pw[pos] = 1.0f;
  }
}

// ---------- pass A: hdn = silu(X Wg^T) * (X Wu^T), gathered rows ----------
__global__ __launch_bounds__(512) void k_moe_gateup(
    const unsigned short* __restrict__ xb,
    const unsigned short* __restrict__ Wgb,
    const unsigned short* __restrict__ Wub,
    const unsigned short* __restrict__ Sgb,
    const unsigned short* __restrict__ Sub,
    const int* __restrict__ pt,
    const int* __restrict__ seg,
    unsigned short* __restrict__ hdn) {
  __shared__ alignas(16) unsigned short sA[128*64];
  __shared__ alignas(16) unsigned short sBg[128*64];
  __shared__ alignas(16) unsigned short sBu[128*64];
  const int tid = threadIdx.x;
  const int bn = blockIdx.x, bm = blockIdx.y;
  const int row0 = bm * 128, n0 = bn * 128;
  int e = 0;
  while (e < 8 && row0 >= seg[e+1]) ++e;
  const unsigned short* Bg = (e < 8) ? Wgb + (size_t)e * kIP * kH : Sgb;
  const unsigned short* Bu = (e < 8) ? Wub + (size_t)e * kIP * kH : Sub;

  const int sr = tid >> 3, su = tid & 7;
  const int sw = (su ^ (sr & 7)) * 8;      // XOR-swizzled 16B unit
  const int tk0 = pt[row0 + sr];
  const int tk1 = pt[row0 + sr + 64];
  const unsigned short* a0 = xb + (size_t)tk0 * kH + su * 8;
  const unsigned short* a1 = xb + (size_t)tk1 * kH + su * 8;
  const unsigned short* g0 = Bg + (size_t)(n0 + sr) * kH + su * 8;
  const unsigned short* g1 = Bg + (size_t)(n0 + sr + 64) * kH + su * 8;
  const unsigned short* uu0 = Bu + (size_t)(n0 + sr) * kH + su * 8;
  const unsigned short* uu1 = Bu + (size_t)(n0 + sr + 64) * kH + su * 8;
  const int p0 = sr * 64 + sw;
  const int p1 = (sr + 64) * 64 + sw;      // (sr+64)&7 == sr&7

  const int w = tid >> 6, l = tid & 63;
  const int wm = (w >> 2) * 64;            // 2 waves over M
  const int wn = (w & 3) * 32;             // 4 waves over N
  const int lr = l & 15, lk = l >> 4;

  f32x4 ag[4][2] = {}; f32x4 au[4][2] = {};

  for (int k0 = 0; k0 < kH; k0 += 64) {
    __syncthreads();
    *(u16x8*)&sA[p0]  = *(const u16x8*)(a0 + k0);
    *(u16x8*)&sA[p1]  = *(const u16x8*)(a1 + k0);
    *(u16x8*)&sBg[p0] = *(const u16x8*)(g0 + k0);
    *(u16x8*)&sBg[p1] = *(const u16x8*)(g1 + k0);
    *(u16x8*)&sBu[p0] = *(const u16x8*)(uu0 + k0);
    *(u16x8*)&sBu[p1] = *(const u16x8*)(uu1 + k0);
    __syncthreads();
    #pragma unroll
    for (int kc = 0; kc < 2; ++kc) {
      const int ul = kc * 4 + lk;
      bf16x8 af[4], gf[2], uf[2];
      #pragma unroll
      for (int fm = 0; fm < 4; ++fm) {
        int r = wm + fm * 16 + lr;
        af[fm] = *reinterpret_cast<const bf16x8*>(&sA[r * 64 + ((ul ^ (r & 7)) * 8)]);
      }
      #pragma unroll
      for (int fn = 0; fn < 2; ++fn) {
        int r = wn + fn * 16 + lr;
        int o = r * 64 + ((ul ^ (r & 7)) * 8);
        gf[fn] = *reinterpret_cast<const bf16x8*>(&sBg[o]);
        uf[fn] = *reinterpret_cast<const bf16x8*>(&sBu[o]);
      }
      #pragma unroll
      for (int fm = 0; fm < 4; ++fm) {
        #pragma unroll
        for (int fn = 0; fn < 2; ++fn) {
          ag[fm][fn] = __builtin_amdgcn_mfma_f32_16x16x32_bf16(af[fm], gf[fn], ag[fm][fn], 0, 0, 0);
          au[fm][fn] = __builtin_amdgcn_mfma_f32_16x16x32_bf16(af[fm], uf[fn], au[fm][fn], 0, 0, 0);
        }
      }
    }
  }
  #pragma unroll
  for (int fm = 0; fm < 4; ++fm) {
    #pragma unroll
    for (int fn = 0; fn < 2; ++fn) {
      #pragma unroll
      for (int j = 0; j < 4; ++j) {
        int r = wm + fm * 16 + lk * 4 + j;
        int c = wn + fn * 16 + lr;
        float g = ag[fm][fn][j], u = au[fm][fn][j];
        float h = g / (1.f + __expf(-g)) * u;
        hdn[(size_t)(row0 + r) * kIP + (n0 + c)] = f2bf(h);
      }
    }
  }
}

// ---------- pass B: y[token] += wt * (hdn @ Wd^T) ----------
__global__ __launch_bounds__(256) void k_moe_down(
    const unsigned short* __restrict__ hdn,
    const unsigned short* __restrict__ Wdb,
    const unsigned short* __restrict__ Sdb,
    const int* __restrict__ pt,
    const float* __restrict__ pw,
    const int* __restrict__ seg,
    float* __restrict__ out) {
  __shared__ alignas(16) unsigned short sA[128*64];
  __shared__ alignas(16) unsigned short sB[128*64];
  const int tid = threadIdx.x;
  const int bn = blockIdx.x, bm = blockIdx.y;
  const int row0 = bm * 128, n0 = bn * 128;
  int e = 0;
  while (e < 8 && row0 >= seg[e+1]) ++e;
  const unsigned short* Bd = (e < 8) ? Wdb + (size_t)e * kH * kIP : Sdb;

  const int sr = tid >> 3, su = tid & 7;
  const unsigned short* pa[4]; const unsigned short* pb[4]; int ph[4];
  #pragma unroll
  for (int i = 0; i < 4; ++i) {
    int r = sr + i * 32;
    pa[i] = hdn + (size_t)(row0 + r) * kIP + su * 8;
    pb[i] = Bd + (size_t)(n0 + r) * kIP + su * 8;
    ph[i] = r * 64 + ((su ^ (r & 7)) * 8);
  }
  const int w = tid >> 6, l = tid & 63;
  const int wm = (w >> 1) * 64, wn = (w & 1) * 64;
  const int lr = l & 15, lk = l >> 4;
  f32x4 acc[4][4] = {};

  for (int k0 = 0; k0 < kIP; k0 += 64) {
    __syncthreads();
    #pragma unroll
    for (int i = 0; i < 4; ++i) {
      *(u16x8*)&sA[ph[i]] = *(const u16x8*)(pa[i] + k0);
      *(u16x8*)&sB[ph[i]] = *(const u16x8*)(pb[i] + k0);
    }
    __syncthreads();
    #pragma unroll
    for (int kc = 0; kc < 2; ++kc) {
      const int ul = kc * 4 + lk;
      bf16x8 af[4], bfr[4];
      #pragma unroll
      for (int fm = 0; fm < 4; ++fm) {
        int r = wm + fm * 16 + lr;
        af[fm] = *reinterpret_cast<const bf16x8*>(&sA[r * 64 + ((ul ^ (r & 7)) * 8)]);
      }
      #pragma unroll
      for (int fn = 0; fn < 4; ++fn) {
        int r = wn + fn * 16 + lr;
        bfr[fn] = *reinterpret_cast<const bf16x8*>(&sB[r * 64 + ((ul ^ (r & 7)) * 8)]);
      }
      #pragma unroll
      for (int fm = 0; fm < 4; ++fm) {
        #pragma unroll
        for (int fn = 0; fn < 4; ++fn)
          acc[fm][fn] = __builtin_amdgcn_mfma_f32_16x16x32_bf16(af[fm], bfr[fn], acc[fm][fn], 0, 0, 0);
      }
    }
  }
  #pragma unroll
  for (int fm = 0; fm < 4; ++fm) {
    #pragma unroll
    for (int j = 0; j < 4; ++j) {
      int r = wm + fm * 16 + lk * 4 + j;
      int prr = row0 + r;
      float wt = pw[prr];
      if (wt != 0.f) {
        int tk = pt[prr];
        float* orow = out + (size_t)tk * kH + n0;
        #pragma unroll
        for (int fn = 0; fn < 4; ++fn)
          atomicAdd(orow + wn + fn * 16 + lr, acc[fm][fn][j] * wt);
      }
    }
  }
}

extern "C" void kernel_launch(void* const* d_in, const int* in_sizes, int n_in,
                              void* d_out, int out_size, void* d_ws, size_t ws_size,
                              hipStream_t stream) {
  const float* x  = (const float*)d_in[0];
  const float* gw = (const float*)d_in[1];
  const float* Wg = (const float*)d_in[2];
  const float* Wu = (const float*)d_in[3];
  const float* Wd = (const float*)d_in[4];
  const float* Sg = (const float*)d_in[5];
  const float* Su = (const float*)d_in[6];
  const float* Sd = (const float*)d_in[7];
  float* out = (float*)d_out;
  char* ws = (char*)d_ws;
  if (ws_size < WS_NEED) return;   // cannot run — fail cleanly

  unsigned short* xb  = (unsigned short*)(ws + OFF_XB);
  unsigned short* Wgb = (unsigned short*)(ws + OFF_WGB);
  unsigned short* Wub = (unsigned short*)(ws + OFF_WUB);
  unsigned short* Wdb = (unsigned short*)(ws + OFF_WDB);
  unsigned short* Sgb = (unsigned short*)(ws + OFF_SGB);
  unsigned short* Sub = (unsigned short*)(ws + OFF_SUB);
  unsigned short* Sdb = (unsigned short*)(ws + OFF_SDB);
  unsigned short* hdn = (unsigned short*)(ws + OFF_HDN);
  int*   pt  = (int*)(ws + OFF_PT);
  float* pw  = (float*)(ws + OFF_PW);
  int*   cnt = (int*)(ws + OFF_CNT);
  int*   cur = (int*)(ws + OFF_CUR);
  int*   seg = (int*)(ws + OFF_SEG);
  int*   tki = (int*)(ws + OFF_TI);
  float* tkw = (float*)(ws + OFF_TW);

  hipMemsetAsync(d_out, 0, (size_t)out_size * sizeof(float), stream);
  hipMemsetAsync(ws + OFF_PT, 0, OFF_SEG - OFF_PT, stream);   // pair lists + cnt + cur

  k_conv_x<<<(kT * kH / 4) / 256, 256, 0, stream>>>(x, xb);
  k_conv_gateup<<<(kE * kIP * (kH / 4)) / 256, 256, 0, stream>>>(Wg, Wgb, kE);
  k_conv_gateup<<<(kE * kIP * (kH / 4)) / 256, 256, 0, stream>>>(Wu, Wub, kE);
  k_conv_gateup<<<(kIP * (kH / 4)) / 256, 256, 0, stream>>>(Sg, Sgb, 1);
  k_conv_gateup<<<(kIP * (kH / 4)) / 256, 256, 0, stream>>>(Su, Sub, 1);
  k_conv_down<<<(kE * kH * (kIP / 4)) / 256, 256, 0, stream>>>(Wd, Wdb, kE);
  k_conv_down<<<(kH * (kIP / 4)) / 256, 256, 0, stream>>>(Sd, Sdb, 1);

  k_gate<<<kT / 4, 256, 0, stream>>>(x, gw, tki, tkw, cnt);
  k_seg<<<1, 1, 0, stream>>>(cnt, seg, cur);
  k_fill<<<(kT * 3) / 256, 256, 0, stream>>>(tki, tkw, seg, cur, pt, pw);

  dim3 gA(kIP / 128, kPairCap / 128);
  k_moe_gateup<<<gA, 512, 0, stream>>>(xb, Wgb, Wub, Sgb, Sub, pt, seg, hdn);
  dim3 gB(kH / 128, kPairCap / 128);
  k_moe_down<<<gB, 256, 0, stream>>>(hdn, Wdb, Sdb, pt, pw, seg, out);
}